// Round 1
// baseline (408.145 us; speedup 1.0000x reference)
//
#include <hip/hip_runtime.h>

// out[b,o,l] = sum_i x[b,i,k'(l)] * P[i,o,f'(l)],  k'=idx[l]&4095, f'=idx[l]>>12
// Phase 1: xT[b,k,i] = bf16(x[b,i,k])  (coalesced transpose+cast into d_ws)
// Phase 1b: pre-pack P into per-lane MFMA A-fragment layout (expanded K=256)
// Phase 2: register-gathered bf16 MFMA. M=o(64 per wave), N=l(16 per wave),
//          B-fragments gathered global->VGPR (no LDS, no barriers).

typedef __attribute__((ext_vector_type(8))) short short8;
typedef __attribute__((ext_vector_type(4))) float floatx4;

#define NB    64
#define CIN   64
#define COUT  64
#define KDIM  4096
#define LDIM  16384
#define ITERS 8                               // per-wave l-tiles of 16, span 512/block
#define XT_BYTES ((size_t)NB * KDIM * CIN * 2)  // 33,554,432

__device__ __forceinline__ unsigned short f2bf(float f) {
  union { float f; unsigned u; } v; v.f = f;
  unsigned r = v.u + 0x7FFFu + ((v.u >> 16) & 1u);  // RNE
  return (unsigned short)(r >> 16);
}

__global__ __launch_bounds__(256) void transpose_bf16(const float* __restrict__ x,
                                                      unsigned short* __restrict__ xt) {
  __shared__ float tile[64 * 65];  // [i][k], +1 pad
  const int t = threadIdx.x;
  const int b = blockIdx.y;
  const int k0 = blockIdx.x * 64;
  const float4* x4 = (const float4*)x;
#pragma unroll
  for (int p = 0; p < 4; ++p) {
    int i  = p * 16 + (t >> 4);
    int kq = t & 15;
    float4 v = x4[(size_t)(b * CIN + i) * (KDIM / 4) + (k0 >> 2) + kq];
    tile[i * 65 + kq * 4 + 0] = v.x;
    tile[i * 65 + kq * 4 + 1] = v.y;
    tile[i * 65 + kq * 4 + 2] = v.z;
    tile[i * 65 + kq * 4 + 3] = v.w;
  }
  __syncthreads();
  unsigned int* xt32 = (unsigned int*)xt;
  const int ip = (t & 31) * 2;  // pair of i's packed into one u32 store
#pragma unroll
  for (int p = 0; p < 8; ++p) {
    int k = p * 8 + (t >> 5);
    unsigned lo = f2bf(tile[ip * 65 + k]);
    unsigned hi = f2bf(tile[(ip + 1) * 65 + k]);
    xt32[((size_t)b * KDIM + k0 + k) * (CIN / 2) + (ip >> 1)] = lo | (hi << 16);
  }
}

// Pre-pack A' fragments: pb[((mt*8+kt)*64 + lane)*8 + j] = bf16(P[i][o][g])
// with o = mt*16 + (lane&15), s = kt*32 + (lane>>4)*8 + j, i = s&63, g = s>>6.
// Each wave in gemm then loads afrag[mt][kt] as one coalesced dwordx4 per lane.
__global__ __launch_bounds__(256) void prepack_afrag(const float* __restrict__ p,
                                                     unsigned short* __restrict__ pb) {
  const int t = blockIdx.x * 256 + threadIdx.x;  // 0..2047 = (mt*8+kt)*64 + lane
  const int lane = t & 63;
  const int mk = t >> 6;
  const int mt = mk >> 3, kt = mk & 7;
  const int o = mt * 16 + (lane & 15);
  const int quad = lane >> 4;
#pragma unroll
  for (int j = 0; j < 8; ++j) {
    int s = kt * 32 + quad * 8 + j;
    int i = s & 63, g = s >> 6;
    pb[t * 8 + j] = f2bf(p[(i * COUT + o) * 4 + g]);
  }
}

__global__ __launch_bounds__(256, 2) void gemm_reg(const unsigned short* __restrict__ xt,
                                                   const unsigned short* __restrict__ pb,
                                                   const int* __restrict__ idx,
                                                   float* __restrict__ out) {
  const int t = threadIdx.x;
  const int b = blockIdx.y;
  const int w = t >> 6;          // wave id -> which 16-l sub-tile
  const int lane = t & 63;
  const int lane15 = lane & 15;
  const int quad = lane >> 4;

  // A' fragments for all 4 o-tiles x 8 k-tiles: 128 VGPR, loaded coalesced.
  short8 af[4][8];
  {
    const short8* pbv = (const short8*)pb;
#pragma unroll
    for (int mt = 0; mt < 4; ++mt)
#pragma unroll
      for (int kt = 0; kt < 8; ++kt)
        af[mt][kt] = pbv[(mt * 8 + kt) * 64 + lane];
  }

  const int l0 = blockIdx.x * (4 * 16 * ITERS) + w * 16;
  const unsigned short* xb = xt + (size_t)b * KDIM * CIN;

  // Prefetch it=0: gathered row halves for this lane's l (= l0 + lane15).
  // B-frag layout: n = lane&15, k = quad*8+j. Nonzero s-range [64f',64f'+64)
  // => kt = 2f' holds row bytes [quad*16,+16), kt = 2f'+1 holds [64+quad*16,+16).
  int iv = idx[l0 + lane15];
  const short8* row = (const short8*)(xb + (size_t)(iv & (KDIM - 1)) * CIN);
  int fp = iv >> 12;
  short8 ev = row[quad];
  short8 ov = row[4 + quad];

  const short8 z8 = {0, 0, 0, 0, 0, 0, 0, 0};

  for (int it = 0; it < ITERS; ++it) {
    const int fpc = fp;
    const short8 evc = ev, ovc = ov;
    if (it < ITERS - 1) {  // prefetch next tile's gather over this tile's MFMAs
      int iv2 = idx[l0 + (it + 1) * 64 + lane15];
      row = (const short8*)(xb + (size_t)(iv2 & (KDIM - 1)) * CIN);
      fp = iv2 >> 12;
      ev = row[quad];
      ov = row[4 + quad];
    }

    floatx4 acc[4] = {floatx4{0.f, 0.f, 0.f, 0.f}, floatx4{0.f, 0.f, 0.f, 0.f},
                      floatx4{0.f, 0.f, 0.f, 0.f}, floatx4{0.f, 0.f, 0.f, 0.f}};
#pragma unroll
    for (int kt = 0; kt < 8; ++kt) {
      const short8 h = (kt & 1) ? ovc : evc;       // compile-time pick
      const short8 bf = (fpc == (kt >> 1)) ? h : z8;  // per-lane cndmask x4
#pragma unroll
      for (int mt = 0; mt < 4; ++mt)
        acc[mt] = __builtin_amdgcn_mfma_f32_16x16x32_bf16(af[mt][kt], bf, acc[mt], 0, 0, 0);
    }

    // C layout: col(n=l) = lane&15, row(m=o within tile) = quad*4 + r
    const int l = l0 + it * 64 + lane15;
    float* ob = out + (size_t)b * COUT * LDIM + l;
#pragma unroll
    for (int mt = 0; mt < 4; ++mt)
#pragma unroll
      for (int r = 0; r < 4; ++r)
        ob[(size_t)(mt * 16 + quad * 4 + r) * LDIM] = acc[mt][r];
  }
}

extern "C" void kernel_launch(void* const* d_in, const int* in_sizes, int n_in,
                              void* d_out, int out_size, void* d_ws, size_t ws_size,
                              hipStream_t stream) {
  const float* x      = (const float*)d_in[0];   // [64,64,1,4096] fp32
  const float* params = (const float*)d_in[1];   // [64,64,4] fp32
  const int*   idx    = (const int*)d_in[2];     // [16384] int32
  float* out = (float*)d_out;                    // [64,64,1,16384] fp32
  unsigned short* xt = (unsigned short*)d_ws;                       // 33.5 MB
  unsigned short* pb = (unsigned short*)((char*)d_ws + XT_BYTES);   // 32 KB

  transpose_bf16<<<dim3(KDIM / 64, NB), 256, 0, stream>>>(x, xt);
  prepack_afrag<<<dim3(8), 256, 0, stream>>>(params, pb);
  gemm_reg<<<dim3(LDIM / (64 * ITERS), NB), 256, 0, stream>>>(xt, pb, idx, out);
}

// Round 2
// 348.183 us; speedup vs baseline: 1.1722x; 1.1722x over previous
//
#include <hip/hip_runtime.h>

// out[b,o,l] = sum_i x[b,i,k'(l)] * P[i,o,f'(l)],  k'=idx[l]&4095, f'=idx[l]>>12
// Phase 1: xT[b,k,i] = bf16(x[b,i,k])  (coalesced transpose+cast into d_ws)
// Phase 1b: pre-pack P into per-lane MFMA A-fragment layout (expanded K=256)
// Phase 2: bf16 MFMA with COMPACT LDS B-tile (64 rows x 64 bf16) gathered
//          cooperatively; expanded-K zeros materialized in registers via
//          per-kt cndmask. 4 waves share the tile; gather prefetched 1 iter.

typedef __attribute__((ext_vector_type(8))) short short8;
typedef __attribute__((ext_vector_type(4))) float floatx4;

#define NB    64
#define CIN   64
#define COUT  64
#define KDIM  4096
#define LDIM  16384
#define ITERS 8                                 // l-tiles (of 64) per block
#define BXS2  72                                // compact row stride in bf16 (144 B)
#define XT_BYTES ((size_t)NB * KDIM * CIN * 2)  // 33,554,432

__device__ __forceinline__ unsigned short f2bf(float f) {
  union { float f; unsigned u; } v; v.f = f;
  unsigned r = v.u + 0x7FFFu + ((v.u >> 16) & 1u);  // RNE
  return (unsigned short)(r >> 16);
}

__global__ __launch_bounds__(256) void transpose_bf16(const float* __restrict__ x,
                                                      unsigned short* __restrict__ xt) {
  __shared__ float tile[64 * 65];  // [i][k], +1 pad
  const int t = threadIdx.x;
  const int b = blockIdx.y;
  const int k0 = blockIdx.x * 64;
  const float4* x4 = (const float4*)x;
#pragma unroll
  for (int p = 0; p < 4; ++p) {
    int i  = p * 16 + (t >> 4);
    int kq = t & 15;
    float4 v = x4[(size_t)(b * CIN + i) * (KDIM / 4) + (k0 >> 2) + kq];
    tile[i * 65 + kq * 4 + 0] = v.x;
    tile[i * 65 + kq * 4 + 1] = v.y;
    tile[i * 65 + kq * 4 + 2] = v.z;
    tile[i * 65 + kq * 4 + 3] = v.w;
  }
  __syncthreads();
  unsigned int* xt32 = (unsigned int*)xt;
  const int ip = (t & 31) * 2;  // pair of i's packed into one u32 store
#pragma unroll
  for (int p = 0; p < 8; ++p) {
    int k = p * 8 + (t >> 5);
    unsigned lo = f2bf(tile[ip * 65 + k]);
    unsigned hi = f2bf(tile[(ip + 1) * 65 + k]);
    xt32[((size_t)b * KDIM + k0 + k) * (CIN / 2) + (ip >> 1)] = lo | (hi << 16);
  }
}

// Pre-pack A' fragments: pb[((mt*8+kt)*64 + lane)*8 + j] = bf16(P[i][o][g])
// with o = mt*16 + (lane&15), s = kt*32 + (lane>>4)*8 + j, i = s&63, g = s>>6.
__global__ __launch_bounds__(256) void prepack_afrag(const float* __restrict__ p,
                                                     unsigned short* __restrict__ pb) {
  const int t = blockIdx.x * 256 + threadIdx.x;  // 0..2047 = (mt*8+kt)*64 + lane
  const int lane = t & 63;
  const int mk = t >> 6;
  const int mt = mk >> 3, kt = mk & 7;
  const int o = mt * 16 + (lane & 15);
  const int quad = lane >> 4;
#pragma unroll
  for (int j = 0; j < 8; ++j) {
    int s = kt * 32 + quad * 8 + j;
    int i = s & 63, g = s >> 6;
    pb[t * 8 + j] = f2bf(p[(i * COUT + o) * 4 + g]);
  }
}

__global__ __launch_bounds__(256, 4) void gemm_lds2(const unsigned short* __restrict__ xt,
                                                    const unsigned short* __restrict__ pb,
                                                    const int* __restrict__ idx,
                                                    float* __restrict__ out) {
  __shared__ __align__(16) unsigned short Bx2[64 * BXS2];  // compact rows, 9.2 KB
  __shared__ int fpv[64];

  const int t = threadIdx.x;
  const int b = blockIdx.y;
  const int w = t >> 6;          // wave id = o-tile
  const int lane = t & 63;
  const int lane15 = lane & 15;
  const int quad = lane >> 4;

  // A' fragments for THIS wave's o-tile only: 32 VGPRs, coalesced L2-hot loads.
  short8 af[8];
  {
    const short8* pbv = (const short8*)pb;
#pragma unroll
    for (int kt = 0; kt < 8; ++kt)
      af[kt] = pbv[(w * 8 + kt) * 64 + lane];
  }

  const unsigned short* xb = xt + (size_t)b * KDIM * CIN;
  const int u = t & 3;           // chunk owner within row (32 B each)
  const int lrow = t >> 2;       // l-row within 64-tile

  // Prefetch it=0 gather into registers.
  uint4 d0, d1; int fp;
  {
    const int l_base = blockIdx.x * (ITERS * 64);
    const int iv = idx[l_base + lrow];
    const uint4* xrow = (const uint4*)(xb + (size_t)(iv & (KDIM - 1)) * CIN);
    d0 = xrow[2 * u];
    d1 = xrow[2 * u + 1];
    fp = iv >> 12;
  }

  const short8 z8 = {0, 0, 0, 0, 0, 0, 0, 0};

  for (int it = 0; it < ITERS; ++it) {
    __syncthreads();  // previous iteration's LDS reads complete
    *(uint4*)&Bx2[lrow * BXS2 + u * 16]     = d0;
    *(uint4*)&Bx2[lrow * BXS2 + u * 16 + 8] = d1;
    if (u == 0) fpv[lrow] = fp;
    __syncthreads();

    if (it + 1 < ITERS) {  // prefetch next tile's gather over this tile's compute
      const int l_base = (blockIdx.x * ITERS + it + 1) * 64;
      const int iv = idx[l_base + lrow];
      const uint4* xrow = (const uint4*)(xb + (size_t)(iv & (KDIM - 1)) * CIN);
      d0 = xrow[2 * u];
      d1 = xrow[2 * u + 1];
      fp = iv >> 12;
    }

    // ---- MFMA: D[o][l] += A'[o][s] * B'[s][l], zeros expanded in-register ----
    floatx4 acc[4] = {floatx4{0.f, 0.f, 0.f, 0.f}, floatx4{0.f, 0.f, 0.f, 0.f},
                      floatx4{0.f, 0.f, 0.f, 0.f}, floatx4{0.f, 0.f, 0.f, 0.f}};
#pragma unroll
    for (int nt = 0; nt < 4; ++nt) {
      const int lr = nt * 16 + lane15;
      const short8 ev = *(const short8*)&Bx2[lr * BXS2 + quad * 8];       // c in [q*8,+8)
      const short8 ov = *(const short8*)&Bx2[lr * BXS2 + 32 + quad * 8];  // c in [32+q*8,+8)
      const int fpl = fpv[lr];
#pragma unroll
      for (int kt = 0; kt < 8; ++kt) {
        const short8 h  = (kt & 1) ? ov : ev;           // compile-time pick
        const short8 bf = (fpl == (kt >> 1)) ? h : z8;  // per-lane cndmask x4
        acc[nt] = __builtin_amdgcn_mfma_f32_16x16x32_bf16(af[kt], bf, acc[nt], 0, 0, 0);
      }
    }

    // C layout: col(n=l) = lane&15, row(m=o within tile) = quad*4 + r
    const int l_base = (blockIdx.x * ITERS + it) * 64;
#pragma unroll
    for (int nt = 0; nt < 4; ++nt) {
      const int l = l_base + nt * 16 + lane15;
#pragma unroll
      for (int r = 0; r < 4; ++r) {
        const int o = w * 16 + quad * 4 + r;
        out[((size_t)(b * COUT + o)) * LDIM + l] = acc[nt][r];
      }
    }
  }
}

extern "C" void kernel_launch(void* const* d_in, const int* in_sizes, int n_in,
                              void* d_out, int out_size, void* d_ws, size_t ws_size,
                              hipStream_t stream) {
  const float* x      = (const float*)d_in[0];   // [64,64,1,4096] fp32
  const float* params = (const float*)d_in[1];   // [64,64,4] fp32
  const int*   idx    = (const int*)d_in[2];     // [16384] int32
  float* out = (float*)d_out;                    // [64,64,1,16384] fp32
  unsigned short* xt = (unsigned short*)d_ws;                       // 33.5 MB
  unsigned short* pb = (unsigned short*)((char*)d_ws + XT_BYTES);   // 32 KB

  transpose_bf16<<<dim3(KDIM / 64, NB), 256, 0, stream>>>(x, xt);
  prepack_afrag<<<dim3(8), 256, 0, stream>>>(params, pb);
  gemm_lds2<<<dim3(LDIM / (64 * ITERS), NB), 256, 0, stream>>>(xt, pb, idx, out);
}

// Round 3
// 347.996 us; speedup vs baseline: 1.1728x; 1.0005x over previous
//
#include <hip/hip_runtime.h>

// out[b,o,l] = sum_i x[b,i,k'(l)] * P[i,o,f'(l)],  k'=idx[l]&4095, f'=idx[l]>>12
// Phase 1: xT[b,k,i] = bf16(x[b,i,k])  (coalesced transpose+cast into d_ws)
// Phase 1b: pre-pack P into per-lane MFMA A-fragment layout (expanded K=256)
// Phase 2: bf16 MFMA, compact LDS B-tile, DOUBLE-BUFFERED with a single raw
//          s_barrier per iter. No vmcnt(0) in the loop: gathers issued before
//          stores so the compiler's counted vmcnt leaves stores in flight.

typedef __attribute__((ext_vector_type(8))) short short8;
typedef __attribute__((ext_vector_type(4))) float floatx4;

#define NB    64
#define CIN   64
#define COUT  64
#define KDIM  4096
#define LDIM  16384
#define ITERS 8                                 // l-tiles (of 64) per block
#define BXS2  72                                // compact row stride in bf16 (144 B)
#define XT_BYTES ((size_t)NB * KDIM * CIN * 2)  // 33,554,432

__device__ __forceinline__ unsigned short f2bf(float f) {
  union { float f; unsigned u; } v; v.f = f;
  unsigned r = v.u + 0x7FFFu + ((v.u >> 16) & 1u);  // RNE
  return (unsigned short)(r >> 16);
}

__global__ __launch_bounds__(256) void transpose_bf16(const float* __restrict__ x,
                                                      unsigned short* __restrict__ xt) {
  __shared__ float tile[64 * 65];  // [i][k], +1 pad
  const int t = threadIdx.x;
  const int b = blockIdx.y;
  const int k0 = blockIdx.x * 64;
  const float4* x4 = (const float4*)x;
#pragma unroll
  for (int p = 0; p < 4; ++p) {
    int i  = p * 16 + (t >> 4);
    int kq = t & 15;
    float4 v = x4[(size_t)(b * CIN + i) * (KDIM / 4) + (k0 >> 2) + kq];
    tile[i * 65 + kq * 4 + 0] = v.x;
    tile[i * 65 + kq * 4 + 1] = v.y;
    tile[i * 65 + kq * 4 + 2] = v.z;
    tile[i * 65 + kq * 4 + 3] = v.w;
  }
  __syncthreads();
  unsigned int* xt32 = (unsigned int*)xt;
  const int ip = (t & 31) * 2;  // pair of i's packed into one u32 store
#pragma unroll
  for (int p = 0; p < 8; ++p) {
    int k = p * 8 + (t >> 5);
    unsigned lo = f2bf(tile[ip * 65 + k]);
    unsigned hi = f2bf(tile[(ip + 1) * 65 + k]);
    xt32[((size_t)b * KDIM + k0 + k) * (CIN / 2) + (ip >> 1)] = lo | (hi << 16);
  }
}

// Pre-pack A' fragments: pb[((mt*8+kt)*64 + lane)*8 + j] = bf16(P[i][o][g])
// with o = mt*16 + (lane&15), s = kt*32 + (lane>>4)*8 + j, i = s&63, g = s>>6.
__global__ __launch_bounds__(256) void prepack_afrag(const float* __restrict__ p,
                                                     unsigned short* __restrict__ pb) {
  const int t = blockIdx.x * 256 + threadIdx.x;  // 0..2047 = (mt*8+kt)*64 + lane
  const int lane = t & 63;
  const int mk = t >> 6;
  const int mt = mk >> 3, kt = mk & 7;
  const int o = mt * 16 + (lane & 15);
  const int quad = lane >> 4;
#pragma unroll
  for (int j = 0; j < 8; ++j) {
    int s = kt * 32 + quad * 8 + j;
    int i = s & 63, g = s >> 6;
    pb[t * 8 + j] = f2bf(p[(i * COUT + o) * 4 + g]);
  }
}

__global__ __launch_bounds__(256, 4) void gemm_db(const unsigned short* __restrict__ xt,
                                                  const unsigned short* __restrict__ pb,
                                                  const int* __restrict__ idx,
                                                  float* __restrict__ out) {
  __shared__ __align__(16) unsigned short Bx[2][64 * BXS2];  // 2 x 9.2 KB
  __shared__ int fpv[2][64];

  const int t = threadIdx.x;
  const int b = blockIdx.y;
  const int w = t >> 6;          // wave id = o-tile
  const int lane = t & 63;
  const int lane15 = lane & 15;
  const int quad = lane >> 4;

  // A' fragments for THIS wave's o-tile only: 32 VGPRs, coalesced L2-hot loads.
  short8 af[8];
  {
    const short8* pbv = (const short8*)pb;
#pragma unroll
    for (int kt = 0; kt < 8; ++kt)
      af[kt] = pbv[(w * 8 + kt) * 64 + lane];
  }

  const unsigned short* xb = xt + (size_t)b * KDIM * CIN;
  const int u = t & 3;           // chunk owner within row (32 B each)
  const int lrow = t >> 2;       // l-row within 64-tile
  const int lb0 = blockIdx.x * (ITERS * 64);

  // Prologue: rows(0) + idx(1) in flight.
  uint4 d0, d1; int fp, ivn;
  {
    const int iv0 = idx[lb0 + lrow];
    const uint4* r0 = (const uint4*)(xb + (size_t)(iv0 & (KDIM - 1)) * CIN);
    d0 = r0[2 * u];
    d1 = r0[2 * u + 1];
    fp = iv0 >> 12;
    ivn = idx[lb0 + 64 + lrow];  // iv(1)
  }

  const short8 z8 = {0, 0, 0, 0, 0, 0, 0, 0};

  for (int it = 0; it < ITERS; ++it) {
    const int p = it & 1;
    // Stage tile(it). Compiler waits a COUNTED vmcnt here (rows(it) are the
    // oldest outstanding vmem); stores(it-1) remain in flight.
    *(uint4*)&Bx[p][lrow * BXS2 + u * 16]     = d0;
    *(uint4*)&Bx[p][lrow * BXS2 + u * 16 + 8] = d1;
    if (u == 0) fpv[p][lrow] = fp;
    asm volatile("s_waitcnt lgkmcnt(0)" ::: "memory");  // ds_writes visible
    __builtin_amdgcn_s_barrier();
    asm volatile("" ::: "memory");

    // Prefetch rows(it+1) (addr from already-loaded ivn) + idx(it+2).
    // Issued BEFORE this iter's stores so later counted waits never drain stores.
    if (it + 1 < ITERS) {
      fp = ivn >> 12;
      const uint4* rn = (const uint4*)(xb + (size_t)(ivn & (KDIM - 1)) * CIN);
      d0 = rn[2 * u];
      d1 = rn[2 * u + 1];
      if (it + 2 < ITERS) ivn = idx[lb0 + (it + 2) * 64 + lrow];
    }

    // ---- MFMA: D[o][l] += A'[o][s] * B'[s][l], zeros expanded in-register ----
    floatx4 acc[4] = {floatx4{0.f, 0.f, 0.f, 0.f}, floatx4{0.f, 0.f, 0.f, 0.f},
                      floatx4{0.f, 0.f, 0.f, 0.f}, floatx4{0.f, 0.f, 0.f, 0.f}};
#pragma unroll
    for (int nt = 0; nt < 4; ++nt) {
      const int lr = nt * 16 + lane15;
      const short8 ev = *(const short8*)&Bx[p][lr * BXS2 + quad * 8];
      const short8 ov = *(const short8*)&Bx[p][lr * BXS2 + 32 + quad * 8];
      const int fpl = fpv[p][lr];
#pragma unroll
      for (int kt = 0; kt < 8; ++kt) {
        const short8 h  = (kt & 1) ? ov : ev;           // compile-time pick
        const short8 bf = (fpl == (kt >> 1)) ? h : z8;  // per-lane cndmask x4
        acc[nt] = __builtin_amdgcn_mfma_f32_16x16x32_bf16(af[kt], bf, acc[nt], 0, 0, 0);
      }
    }

    // C layout: col(n=l) = lane&15, row(m=o within tile) = quad*4 + r.
    // Nontemporal: out is write-once; keep L2 for the xt gather.
    const int l_base = lb0 + it * 64;
#pragma unroll
    for (int nt = 0; nt < 4; ++nt) {
      const int l = l_base + nt * 16 + lane15;
#pragma unroll
      for (int r = 0; r < 4; ++r) {
        const int o = w * 16 + quad * 4 + r;
        __builtin_nontemporal_store(acc[nt][r], &out[((size_t)(b * COUT + o)) * LDIM + l]);
      }
    }
    // NO trailing barrier: double buffer — next iter writes Bx[p^1], and the
    // barrier above separates this iter's reads from the it+2 overwrite
    // (lgkmcnt(0) before it drains every wave's outstanding LDS reads).
  }
}

extern "C" void kernel_launch(void* const* d_in, const int* in_sizes, int n_in,
                              void* d_out, int out_size, void* d_ws, size_t ws_size,
                              hipStream_t stream) {
  const float* x      = (const float*)d_in[0];   // [64,64,1,4096] fp32
  const float* params = (const float*)d_in[1];   // [64,64,4] fp32
  const int*   idx    = (const int*)d_in[2];     // [16384] int32
  float* out = (float*)d_out;                    // [64,64,1,16384] fp32
  unsigned short* xt = (unsigned short*)d_ws;                       // 33.5 MB
  unsigned short* pb = (unsigned short*)((char*)d_ws + XT_BYTES);   // 32 KB

  transpose_bf16<<<dim3(KDIM / 64, NB), 256, 0, stream>>>(x, xt);
  prepack_afrag<<<dim3(8), 256, 0, stream>>>(params, pb);
  gemm_db<<<dim3(LDIM / (64 * ITERS), NB), 256, 0, stream>>>(xt, pb, idx, out);
}

// Round 4
// 347.777 us; speedup vs baseline: 1.1736x; 1.0006x over previous
//
#include <hip/hip_runtime.h>

// out[b,o,l] = sum_i x[b,i,k'(l)] * P[i,o,f'(l)],  k'=idx[l]&4095, f'=idx[l]>>12
// Phase 1: xT[b,k,i] = bf16(x[b,i,k])  (coalesced transpose+cast into d_ws)
// Phase 1b: pre-pack P into per-lane MFMA A-fragment layout (expanded K=256)
// Phase 2: bf16 MFMA, compact LDS B-tile, double-buffered, counted vmcnt.
//   NEW: bijective XCD swizzle (same-b blocks share one XCD's L2 for xt),
//        ITERS=4 (2x blocks/TLP), contiguous 8-lane row gather,
//        paired independent MFMA chains (kt-outer).

typedef __attribute__((ext_vector_type(8))) short short8;
typedef __attribute__((ext_vector_type(4))) float floatx4;

#define NB    64
#define CIN   64
#define COUT  64
#define KDIM  4096
#define LDIM  16384
#define ITERS 4                                 // l-tiles (of 64) per block
#define BXS2  72                                // compact row stride in bf16 (144 B)
#define XT_BYTES ((size_t)NB * KDIM * CIN * 2)  // 33,554,432

__device__ __forceinline__ unsigned short f2bf(float f) {
  union { float f; unsigned u; } v; v.f = f;
  unsigned r = v.u + 0x7FFFu + ((v.u >> 16) & 1u);  // RNE
  return (unsigned short)(r >> 16);
}

__global__ __launch_bounds__(256) void transpose_bf16(const float* __restrict__ x,
                                                      unsigned short* __restrict__ xt) {
  __shared__ float tile[64 * 65];  // [i][k], +1 pad
  const int t = threadIdx.x;
  const int b = blockIdx.y;
  const int k0 = blockIdx.x * 64;
  const float4* x4 = (const float4*)x;
#pragma unroll
  for (int p = 0; p < 4; ++p) {
    int i  = p * 16 + (t >> 4);
    int kq = t & 15;
    float4 v = x4[(size_t)(b * CIN + i) * (KDIM / 4) + (k0 >> 2) + kq];
    tile[i * 65 + kq * 4 + 0] = v.x;
    tile[i * 65 + kq * 4 + 1] = v.y;
    tile[i * 65 + kq * 4 + 2] = v.z;
    tile[i * 65 + kq * 4 + 3] = v.w;
  }
  __syncthreads();
  unsigned int* xt32 = (unsigned int*)xt;
  const int ip = (t & 31) * 2;  // pair of i's packed into one u32 store
#pragma unroll
  for (int p = 0; p < 8; ++p) {
    int k = p * 8 + (t >> 5);
    unsigned lo = f2bf(tile[ip * 65 + k]);
    unsigned hi = f2bf(tile[(ip + 1) * 65 + k]);
    xt32[((size_t)b * KDIM + k0 + k) * (CIN / 2) + (ip >> 1)] = lo | (hi << 16);
  }
}

// Pre-pack A' fragments: pb[((mt*8+kt)*64 + lane)*8 + j] = bf16(P[i][o][g])
// with o = mt*16 + (lane&15), s = kt*32 + (lane>>4)*8 + j, i = s&63, g = s>>6.
__global__ __launch_bounds__(256) void prepack_afrag(const float* __restrict__ p,
                                                     unsigned short* __restrict__ pb) {
  const int t = blockIdx.x * 256 + threadIdx.x;  // 0..2047 = (mt*8+kt)*64 + lane
  const int lane = t & 63;
  const int mk = t >> 6;
  const int mt = mk >> 3, kt = mk & 7;
  const int o = mt * 16 + (lane & 15);
  const int quad = lane >> 4;
#pragma unroll
  for (int j = 0; j < 8; ++j) {
    int s = kt * 32 + quad * 8 + j;
    int i = s & 63, g = s >> 6;
    pb[t * 8 + j] = f2bf(p[(i * COUT + o) * 4 + g]);
  }
}

__global__ __launch_bounds__(256, 4) void gemm_v4(const unsigned short* __restrict__ xt,
                                                  const unsigned short* __restrict__ pb,
                                                  const int* __restrict__ idx,
                                                  float* __restrict__ out) {
  __shared__ __align__(16) unsigned short Bx[2][64 * BXS2];  // 2 x 9.2 KB
  __shared__ int fpv[2][64];

  const int t = threadIdx.x;
  // Bijective XCD swizzle (nwg=4096, 8 XCDs): XCD k gets wg' in [512k,512k+512)
  // => each XCD serves 8 full b-slices (8 x 512 KB xt, L2-resident one at a time).
  const int wg  = blockIdx.x + gridDim.x * blockIdx.y;  // 0..4095
  const int wgp = (wg & 7) * 512 + (wg >> 3);
  const int b   = wgp >> 6;   // 64 blocks of same b land on one XCD
  const int xx  = wgp & 63;   // l-chunk within b

  const int w = t >> 6;          // wave id = o-tile
  const int lane = t & 63;
  const int lane15 = lane & 15;
  const int quad = lane >> 4;

  // A' fragments for THIS wave's o-tile only: 32 VGPRs, coalesced L2-hot loads.
  short8 af[8];
  {
    const short8* pbv = (const short8*)pb;
#pragma unroll
    for (int kt = 0; kt < 8; ++kt)
      af[kt] = pbv[(w * 8 + kt) * 64 + lane];
  }

  const unsigned short* xb = xt + (size_t)b * KDIM * CIN;
  const int u  = t & 7;   // 16B chunk within the 128B row (contiguous per row)
  const int r1 = t >> 3;  // row pair: r1 and r1+32
  const int lb0 = xx * (ITERS * 64);

  // Prologue: rows(0) + idx(1) in flight.
  int iv1 = idx[lb0 + r1];
  int iv2 = idx[lb0 + 32 + r1];
  uint4 d0 = ((const uint4*)(xb + (size_t)(iv1 & (KDIM - 1)) * CIN))[u];
  uint4 d1 = ((const uint4*)(xb + (size_t)(iv2 & (KDIM - 1)) * CIN))[u];
  int fp1 = iv1 >> 12, fp2 = iv2 >> 12;
  int ivn1 = idx[lb0 + 64 + r1];
  int ivn2 = idx[lb0 + 96 + r1];

  const short8 z8 = {0, 0, 0, 0, 0, 0, 0, 0};

  for (int it = 0; it < ITERS; ++it) {
    const int p = it & 1;
    // Stage tile(it): counted vmcnt retires only the gathers; prior stores fly on.
    *(uint4*)&Bx[p][r1 * BXS2 + u * 8]        = d0;
    *(uint4*)&Bx[p][(r1 + 32) * BXS2 + u * 8] = d1;
    if (u == 0) { fpv[p][r1] = fp1; fpv[p][r1 + 32] = fp2; }
    asm volatile("s_waitcnt lgkmcnt(0)" ::: "memory");  // writes visible + reads drained
    __builtin_amdgcn_s_barrier();
    asm volatile("" ::: "memory");

    // Prefetch rows(it+1) (addr from already-loaded ivn*) + idx(it+2).
    if (it + 1 < ITERS) {
      fp1 = ivn1 >> 12;
      fp2 = ivn2 >> 12;
      d0 = ((const uint4*)(xb + (size_t)(ivn1 & (KDIM - 1)) * CIN))[u];
      d1 = ((const uint4*)(xb + (size_t)(ivn2 & (KDIM - 1)) * CIN))[u];
      if (it + 2 < ITERS) {
        ivn1 = idx[lb0 + (it + 2) * 64 + r1];
        ivn2 = idx[lb0 + (it + 2) * 64 + 32 + r1];
      }
    }

    // ---- MFMA: kt-outer, two independent acc chains per pass ----
    floatx4 acc[4];
#pragma unroll
    for (int np = 0; np < 2; ++np) {
      const int lrA = (np * 2) * 16 + lane15;
      const int lrB = (np * 2 + 1) * 16 + lane15;
      const short8 evA = *(const short8*)&Bx[p][lrA * BXS2 + quad * 8];
      const short8 ovA = *(const short8*)&Bx[p][lrA * BXS2 + 32 + quad * 8];
      const short8 evB = *(const short8*)&Bx[p][lrB * BXS2 + quad * 8];
      const short8 ovB = *(const short8*)&Bx[p][lrB * BXS2 + 32 + quad * 8];
      const int fA = fpv[p][lrA];
      const int fB = fpv[p][lrB];
      floatx4 a0 = floatx4{0.f, 0.f, 0.f, 0.f};
      floatx4 a1 = floatx4{0.f, 0.f, 0.f, 0.f};
#pragma unroll
      for (int kt = 0; kt < 8; ++kt) {
        const short8 hA = (kt & 1) ? ovA : evA;           // compile-time pick
        const short8 hB = (kt & 1) ? ovB : evB;
        const short8 bA = (fA == (kt >> 1)) ? hA : z8;    // per-lane cndmask
        const short8 bB = (fB == (kt >> 1)) ? hB : z8;
        a0 = __builtin_amdgcn_mfma_f32_16x16x32_bf16(af[kt], bA, a0, 0, 0, 0);
        a1 = __builtin_amdgcn_mfma_f32_16x16x32_bf16(af[kt], bB, a1, 0, 0, 0);
      }
      acc[np * 2]     = a0;
      acc[np * 2 + 1] = a1;
    }

    // C layout: col(n=l) = lane&15, row(m=o within tile) = quad*4 + r.
    const int l_base = lb0 + it * 64;
#pragma unroll
    for (int nt = 0; nt < 4; ++nt) {
      const int l = l_base + nt * 16 + lane15;
#pragma unroll
      for (int r = 0; r < 4; ++r) {
        const int o = w * 16 + quad * 4 + r;
        __builtin_nontemporal_store(acc[nt][r], &out[((size_t)(b * COUT + o)) * LDIM + l]);
      }
    }
  }
}

extern "C" void kernel_launch(void* const* d_in, const int* in_sizes, int n_in,
                              void* d_out, int out_size, void* d_ws, size_t ws_size,
                              hipStream_t stream) {
  const float* x      = (const float*)d_in[0];   // [64,64,1,4096] fp32
  const float* params = (const float*)d_in[1];   // [64,64,4] fp32
  const int*   idx    = (const int*)d_in[2];     // [16384] int32
  float* out = (float*)d_out;                    // [64,64,1,16384] fp32
  unsigned short* xt = (unsigned short*)d_ws;                       // 33.5 MB
  unsigned short* pb = (unsigned short*)((char*)d_ws + XT_BYTES);   // 32 KB

  transpose_bf16<<<dim3(KDIM / 64, NB), 256, 0, stream>>>(x, xt);
  prepack_afrag<<<dim3(8), 256, 0, stream>>>(params, pb);
  gemm_v4<<<dim3(LDIM / (64 * ITERS), NB), 256, 0, stream>>>(xt, pb, idx, out);
}

// Round 6
// 324.347 us; speedup vs baseline: 1.2584x; 1.0722x over previous
//
#include <hip/hip_runtime.h>

// out[b,o,l] = sum_i x[b,i,k'(l)] * P[i,o,f'(l)],  k'=idx[l]&4095, f'=idx[l]>>12
// Phase 1: xT[b,k,i] = bf16(x[b,i,k])  (coalesced transpose+cast into d_ws)
// Phase 1b: pre-pack P into per-lane MFMA A-fragment layout (expanded K=256)
// Phase 2: bf16 MFMA, compact LDS B-tile (single-buffered, 2 barriers/iter).
//   C-tile staged through LDS -> fully-coalesced dwordx4 stores
//   (256 contiguous B per 16 lanes, full 128-B lines, 4 store instrs/wave).

typedef __attribute__((ext_vector_type(8))) short short8;
typedef __attribute__((ext_vector_type(4))) float floatx4;

#define NB    64
#define CIN   64
#define COUT  64
#define KDIM  4096
#define LDIM  16384
#define ITERS 4                                 // l-tiles (of 64) per block
#define BXS2  72                                // B-tile row stride in bf16 (144 B)
#define CSTR  68                                // C-tile row stride in f32 (272 B)
#define XT_BYTES ((size_t)NB * KDIM * CIN * 2)  // 33,554,432

__device__ __forceinline__ unsigned short f2bf(float f) {
  union { float f; unsigned u; } v; v.f = f;
  unsigned r = v.u + 0x7FFFu + ((v.u >> 16) & 1u);  // RNE
  return (unsigned short)(r >> 16);
}

__global__ __launch_bounds__(256) void transpose_bf16(const float* __restrict__ x,
                                                      unsigned short* __restrict__ xt) {
  __shared__ float tile[64 * 65];  // [i][k], +1 pad
  const int t = threadIdx.x;
  const int b = blockIdx.y;
  const int k0 = blockIdx.x * 64;
  const float4* x4 = (const float4*)x;
#pragma unroll
  for (int p = 0; p < 4; ++p) {
    int i  = p * 16 + (t >> 4);
    int kq = t & 15;
    float4 v = x4[(size_t)(b * CIN + i) * (KDIM / 4) + (k0 >> 2) + kq];
    tile[i * 65 + kq * 4 + 0] = v.x;
    tile[i * 65 + kq * 4 + 1] = v.y;
    tile[i * 65 + kq * 4 + 2] = v.z;
    tile[i * 65 + kq * 4 + 3] = v.w;
  }
  __syncthreads();
  unsigned int* xt32 = (unsigned int*)xt;
  const int ip = (t & 31) * 2;  // pair of i's packed into one u32 store
#pragma unroll
  for (int p = 0; p < 8; ++p) {
    int k = p * 8 + (t >> 5);
    unsigned lo = f2bf(tile[ip * 65 + k]);
    unsigned hi = f2bf(tile[(ip + 1) * 65 + k]);
    xt32[((size_t)b * KDIM + k0 + k) * (CIN / 2) + (ip >> 1)] = lo | (hi << 16);
  }
}

// Pre-pack A' fragments: pb[((mt*8+kt)*64 + lane)*8 + j] = bf16(P[i][o][g])
// with o = mt*16 + (lane&15), s = kt*32 + (lane>>4)*8 + j, i = s&63, g = s>>6.
__global__ __launch_bounds__(256) void prepack_afrag(const float* __restrict__ p,
                                                     unsigned short* __restrict__ pb) {
  const int t = blockIdx.x * 256 + threadIdx.x;  // 0..2047 = (mt*8+kt)*64 + lane
  const int lane = t & 63;
  const int mk = t >> 6;
  const int mt = mk >> 3, kt = mk & 7;
  const int o = mt * 16 + (lane & 15);
  const int quad = lane >> 4;
#pragma unroll
  for (int j = 0; j < 8; ++j) {
    int s = kt * 32 + quad * 8 + j;
    int i = s & 63, g = s >> 6;
    pb[t * 8 + j] = f2bf(p[(i * COUT + o) * 4 + g]);
  }
}

__global__ __launch_bounds__(256, 4) void gemm_v5(const unsigned short* __restrict__ xt,
                                                  const unsigned short* __restrict__ pb,
                                                  const int* __restrict__ idx,
                                                  float* __restrict__ out) {
  __shared__ __align__(16) unsigned short Bx[64 * BXS2];  // 9.2 KB, single buffer
  __shared__ int fpv[64];
  __shared__ __align__(16) float Cl[64 * CSTR];           // 17.4 KB C staging

  const int t = threadIdx.x;
  // Bijective XCD swizzle (nwg=4096, 8 XCDs): neutral-at-worst (r4), keep.
  const int wg  = blockIdx.x + gridDim.x * blockIdx.y;  // 0..4095
  const int wgp = (wg & 7) * 512 + (wg >> 3);
  const int b   = wgp >> 6;
  const int xx  = wgp & 63;

  const int w = t >> 6;          // wave id = o-tile
  const int lane = t & 63;
  const int lane15 = lane & 15;
  const int quad = lane >> 4;

  // A' fragments for THIS wave's o-tile only: 32 VGPRs, coalesced L2-hot loads.
  short8 af[8];
  {
    const short8* pbv = (const short8*)pb;
#pragma unroll
    for (int kt = 0; kt < 8; ++kt)
      af[kt] = pbv[(w * 8 + kt) * 64 + lane];
  }

  const unsigned short* xb = xt + (size_t)b * KDIM * CIN;
  const int u  = t & 7;   // 16B chunk within the 128B row (contiguous per row)
  const int r1 = t >> 3;  // row pair: r1 and r1+32
  const int lb0 = xx * (ITERS * 64);

  // Prologue: rows(0) + idx(1) in flight.
  int iv1 = idx[lb0 + r1];
  int iv2 = idx[lb0 + 32 + r1];
  uint4 d0 = ((const uint4*)(xb + (size_t)(iv1 & (KDIM - 1)) * CIN))[u];
  uint4 d1 = ((const uint4*)(xb + (size_t)(iv2 & (KDIM - 1)) * CIN))[u];
  int fp1 = iv1 >> 12, fp2 = iv2 >> 12;
  int ivn1 = idx[lb0 + 64 + r1];
  int ivn2 = idx[lb0 + 96 + r1];

  const short8 z8 = {0, 0, 0, 0, 0, 0, 0, 0};

  for (int it = 0; it < ITERS; ++it) {
    // Stage B tile(it): counted vmcnt retires only the gathers; stores fly on.
    *(uint4*)&Bx[r1 * BXS2 + u * 8]        = d0;
    *(uint4*)&Bx[(r1 + 32) * BXS2 + u * 8] = d1;
    if (u == 0) { fpv[r1] = fp1; fpv[r1 + 32] = fp2; }
    asm volatile("s_waitcnt lgkmcnt(0)" ::: "memory");
    __builtin_amdgcn_s_barrier();
    asm volatile("" ::: "memory");

    // Prefetch rows(it+1) (addr from already-loaded ivn*) + idx(it+2).
    if (it + 1 < ITERS) {
      fp1 = ivn1 >> 12;
      fp2 = ivn2 >> 12;
      d0 = ((const uint4*)(xb + (size_t)(ivn1 & (KDIM - 1)) * CIN))[u];
      d1 = ((const uint4*)(xb + (size_t)(ivn2 & (KDIM - 1)) * CIN))[u];
      if (it + 2 < ITERS) {
        ivn1 = idx[lb0 + (it + 2) * 64 + r1];
        ivn2 = idx[lb0 + (it + 2) * 64 + 32 + r1];
      }
    }

    // ---- MFMA: kt-outer, two independent acc chains per pass ----
    floatx4 acc[4];
#pragma unroll
    for (int np = 0; np < 2; ++np) {
      const int lrA = (np * 2) * 16 + lane15;
      const int lrB = (np * 2 + 1) * 16 + lane15;
      const short8 evA = *(const short8*)&Bx[lrA * BXS2 + quad * 8];
      const short8 ovA = *(const short8*)&Bx[lrA * BXS2 + 32 + quad * 8];
      const short8 evB = *(const short8*)&Bx[lrB * BXS2 + quad * 8];
      const short8 ovB = *(const short8*)&Bx[lrB * BXS2 + 32 + quad * 8];
      const int fA = fpv[lrA];
      const int fB = fpv[lrB];
      floatx4 a0 = floatx4{0.f, 0.f, 0.f, 0.f};
      floatx4 a1 = floatx4{0.f, 0.f, 0.f, 0.f};
#pragma unroll
      for (int kt = 0; kt < 8; ++kt) {
        const short8 hA = (kt & 1) ? ovA : evA;           // compile-time pick
        const short8 hB = (kt & 1) ? ovB : evB;
        const short8 bA = (fA == (kt >> 1)) ? hA : z8;    // per-lane cndmask
        const short8 bB = (fB == (kt >> 1)) ? hB : z8;
        a0 = __builtin_amdgcn_mfma_f32_16x16x32_bf16(af[kt], bA, a0, 0, 0, 0);
        a1 = __builtin_amdgcn_mfma_f32_16x16x32_bf16(af[kt], bB, a1, 0, 0, 0);
      }
      acc[np * 2]     = a0;
      acc[np * 2 + 1] = a1;
    }
    // All Bx reads of this wave are retired before the lgkmcnt below, so the
    // next iteration's Bx overwrite (after that barrier) is race-free.

    // ---- C -> LDS (2-way bank pattern, free) ----
#pragma unroll
    for (int nt = 0; nt < 4; ++nt)
#pragma unroll
      for (int r = 0; r < 4; ++r)
        Cl[(w * 16 + quad * 4 + r) * CSTR + nt * 16 + lane15] = acc[nt][r];
    asm volatile("s_waitcnt lgkmcnt(0)" ::: "memory");
    __builtin_amdgcn_s_barrier();
    asm volatile("" ::: "memory");

    // ---- C -> global: 16 lanes cover 256 contiguous B of one o-row ----
    const int l_base = lb0 + it * 64;
    const int cc = (t & 15) * 4;     // float chunk within row
    const int rr = t >> 4;           // 0..15
#pragma unroll
    for (int pp = 0; pp < 4; ++pp) {
      const int row = pp * 16 + rr;  // o within block tile
      floatx4 v = *(const floatx4*)&Cl[row * CSTR + cc];
      __builtin_nontemporal_store(v,
          (floatx4*)&out[((size_t)(b * COUT + row)) * LDIM + l_base + cc]);
    }
    // Next iter's Bx/C writes are separated from this phase's LDS reads by the
    // top-of-loop lgkmcnt(0)+barrier.
  }
}

extern "C" void kernel_launch(void* const* d_in, const int* in_sizes, int n_in,
                              void* d_out, int out_size, void* d_ws, size_t ws_size,
                              hipStream_t stream) {
  const float* x      = (const float*)d_in[0];   // [64,64,1,4096] fp32
  const float* params = (const float*)d_in[1];   // [64,64,4] fp32
  const int*   idx    = (const int*)d_in[2];     // [16384] int32
  float* out = (float*)d_out;                    // [64,64,1,16384] fp32
  unsigned short* xt = (unsigned short*)d_ws;                       // 33.5 MB
  unsigned short* pb = (unsigned short*)((char*)d_ws + XT_BYTES);   // 32 KB

  transpose_bf16<<<dim3(KDIM / 64, NB), 256, 0, stream>>>(x, xt);
  prepack_afrag<<<dim3(8), 256, 0, stream>>>(params, pb);
  gemm_v5<<<dim3(LDIM / (64 * ITERS), NB), 256, 0, stream>>>(xt, pb, idx, out);
}